// Round 5
// baseline (463.605 us; speedup 1.0000x reference)
//
#include <hip/hip_runtime.h>
#include <math.h>

// Problem constants
#define HH 1280
#define WW 720
#define NWB 36
#define NBLK 2304               // 64 x 36 gate/block grid
#define OUT_IMG (3*5120*2880)   // 44236800
#define X1N (640*360)           // x1p plane stride

__device__ __forceinline__ int iclamp(int v, int lo, int hi) {
  return v < lo ? lo : (v > hi ? hi : v);
}
__device__ __forceinline__ float fast_tanh(float x) {
  float e = __expf(2.0f * x);
  return 1.0f - __fdividef(2.0f, e + 1.0f);
}

// LDS layouts (union: branch is block-uniform)
struct LightSm {
  float in_s[3][22][28];   // zero-padded block; row stride 28 words (28 mod 32 = -4
                           // per h -> 8 disjoint bank-quads for b128: conflict-free)
  float w4[12*27*4];       // [ocg=(c*4+r1)][k=ic*9+ky*3+kx][r2]
  float bias[48];
};
struct GateASm {
  float w1p[4*27*4];       // [ocg][k][r2] for conv1 (16 oc)
  float b1s[16];
};
union SmU { LightSm l; GateASm g; };

// ---------------------------------------------------------------------------
// K1: even blocks = light expert (conv3x3 3->48 + pixel_shuffle + clamp+0.4),
//     odd blocks  = gate stage A (conv1+tanh+maxpool) -> x1p[16][640][360] in ws.
// mask = sigmoid(..) > 1.0 is always False -> complex expert is dead code.
// ---------------------------------------------------------------------------
__global__ __launch_bounds__(256) void k1_light_gateA(
    const float* __restrict__ inp,
    const float* __restrict__ w1, const float* __restrict__ b1,
    const float* __restrict__ wl, const float* __restrict__ bl,
    float* __restrict__ out, float* __restrict__ x1p) {
  __shared__ SmU sm;
  const int tid = threadIdx.x;
  const int l = blockIdx.x >> 1;

  if ((blockIdx.x & 1) == 0) {
    // ============================ LIGHT EXPERT ============================
    const int bi = l / NWB, bj = l % NWB;
    float* in_f = &sm.l.in_s[0][0][0];
    for (int i = tid; i < 3*22*28; i += 256) in_f[i] = 0.0f;
    for (int i = tid; i < 48*27; i += 256) {
      int oc = i / 27, k = i - oc*27;
      sm.l.w4[((oc >> 2)*27 + k)*4 + (oc & 3)] = wl[i];
    }
    if (tid < 48) sm.l.bias[tid] = bl[tid];
    __syncthreads();
    for (int i = tid; i < 300; i += 256) {     // float4 global stage
      int x4 = i % 5, r = (i / 5) % 20, c = i / 100;
      float4 v = *(const float4*)&inp[(c*HH + bi*20 + r)*WW + bj*20 + 4*x4];
      float* dst = &sm.l.in_s[c][r+1][1 + 4*x4];
      dst[0]=v.x; dst[1]=v.y; dst[2]=v.z; dst[3]=v.w;
    }
    __syncthreads();

    if (tid < 240) {
      // h-major: <=6 distinct row addrs per wave (12-lane broadcast each)
      const int h = tid / 12, ocg = tid % 12;
      const float4* wq = (const float4*)&sm.l.w4[ocg*27*4];
      float b0 = sm.l.bias[ocg*4+0], b1v = sm.l.bias[ocg*4+1];
      float b2v = sm.l.bias[ocg*4+2], b3v = sm.l.bias[ocg*4+3];
      float acc0[20], acc1[20], acc2[20], acc3[20];
      #pragma unroll
      for (int w = 0; w < 20; ++w) { acc0[w]=b0; acc1[w]=b1v; acc2[w]=b2v; acc3[w]=b3v; }

      #pragma unroll
      for (int ic = 0; ic < 3; ++ic)
        #pragma unroll
        for (int ky = 0; ky < 3; ++ky) {
          const float* row = &sm.l.in_s[ic][h + ky][0];
          float r[24];
          #pragma unroll
          for (int j = 0; j < 6; ++j) {
            float4 v = ((const float4*)row)[j];   // ds_read_b128, conflict-free
            r[j*4+0]=v.x; r[j*4+1]=v.y; r[j*4+2]=v.z; r[j*4+3]=v.w;
          }
          float4 wa = wq[ic*9 + ky*3 + 0];
          float4 wb = wq[ic*9 + ky*3 + 1];
          float4 wc = wq[ic*9 + ky*3 + 2];
          #pragma unroll
          for (int w = 0; w < 20; ++w) {
            float x0 = r[w], x1 = r[w+1], x2 = r[w+2];
            acc0[w] += x0*wa.x + x1*wb.x + x2*wc.x;
            acc1[w] += x0*wa.y + x1*wb.y + x2*wc.y;
            acc2[w] += x0*wa.z + x1*wb.z + x2*wc.z;
            acc3[w] += x0*wa.w + x1*wb.w + x2*wc.w;
          }
        }

      // pixel_shuffle: out[c][4h+r1][4w+r2]; r2 lanes -> float4 store
      const int c = ocg >> 2, r1 = ocg & 3;
      float4* obase = (float4*)&out[(c*5120 + bi*80 + 4*h + r1)*2880 + bj*80];
      #pragma unroll
      for (int w = 0; w < 20; ++w) {
        float4 v;
        v.x = fminf(fmaxf(acc0[w], 0.0f), 0.6f) + 0.4f;
        v.y = fminf(fmaxf(acc1[w], 0.0f), 0.6f) + 0.4f;
        v.z = fminf(fmaxf(acc2[w], 0.0f), 0.6f) + 0.4f;
        v.w = fminf(fmaxf(acc3[w], 0.0f), 0.6f) + 0.4f;
        obase[w] = v;
      }
    }
  } else {
    // ===================== GATE STAGE A -> x1p (ws) ======================
    const int oy = l / NWB, ox = l % NWB;
    for (int i = tid; i < 16*27; i += 256) {
      int oc = i / 27, k = i - oc*27;
      sm.g.w1p[((oc >> 2)*27 + k)*4 + (oc & 3)] = w1[i];
    }
    if (tid < 16) sm.g.b1s[tid] = b1[tid];
    __syncthreads();

    // 400 tasks: 4 oc-groups x 10x10 interior pixels of this block's x1p tile
    for (int t = tid; t < 400; t += 256) {
      const int ocg = t / 100, pos = t - ocg*100;
      const int ly = pos / 10, lx = pos - ly*10;
      const int y1 = 10*oy + ly, x1 = 10*ox + lx;
      int gy[4], gx[4];
      #pragma unroll
      for (int d = 0; d < 4; ++d) {
        gy[d] = iclamp(2*y1 - 1 + d, 0, HH-1);   // edge_pad1 baked in
        gx[d] = iclamp(2*x1 - 1 + d, 0, WW-1);
      }
      float p[3][4][4];
      #pragma unroll
      for (int ic = 0; ic < 3; ++ic) {
        #pragma unroll
        for (int d = 0; d < 4; ++d) {
          const float* rowp = &inp[(ic*HH + gy[d])*WW];   // L1-resident reuse
          #pragma unroll
          for (int e = 0; e < 4; ++e) p[ic][d][e] = rowp[gx[e]];
        }
      }
      const float4* wv = (const float4*)&sm.g.w1p[ocg*27*4];
      float acc[4][4];   // [window][r2]
      #pragma unroll
      for (int win = 0; win < 4; ++win)
        #pragma unroll
        for (int r = 0; r < 4; ++r) acc[win][r] = sm.g.b1s[ocg*4 + r];
      #pragma unroll
      for (int ic = 0; ic < 3; ++ic)
        #pragma unroll
        for (int ky = 0; ky < 3; ++ky)
          #pragma unroll
          for (int kx = 0; kx < 3; ++kx) {
            float4 wq = wv[ic*9 + ky*3 + kx];
            #pragma unroll
            for (int sy = 0; sy < 2; ++sy)
              #pragma unroll
              for (int sx = 0; sx < 2; ++sx) {
                float pv = p[ic][sy+ky][sx+kx];
                acc[sy*2+sx][0] += pv*wq.x;
                acc[sy*2+sx][1] += pv*wq.y;
                acc[sy*2+sx][2] += pv*wq.z;
                acc[sy*2+sx][3] += pv*wq.w;
              }
          }
      #pragma unroll
      for (int r = 0; r < 4; ++r) {
        float m = fmaxf(fmaxf(acc[0][r], acc[1][r]), fmaxf(acc[2][r], acc[3][r]));
        x1p[(ocg*4 + r)*X1N + y1*360 + x1] = fast_tanh(m);  // maxpool(tanh)==tanh(maxpool)
      }
    }
  }
}

// ---------------------------------------------------------------------------
// K2: gate stages B+C. One wave per gate output. Reads x1p from global (L2),
// weights broadcast from LDS, wave-shuffle reduction -> sigmoid -> cv.
// ---------------------------------------------------------------------------
__global__ __launch_bounds__(64) void k2_gateBC(
    const float* __restrict__ x1p,
    const float* __restrict__ w2, const float* __restrict__ b2,
    const float* __restrict__ w3, const float* __restrict__ b3,
    float* __restrict__ cv) {
  __shared__ float w2p[8*16*3*4];   // [oc2][ic][ky][kx0..2,pad]
  __shared__ float w3s[200];
  __shared__ float b2s[8];
  __shared__ float b3s_;
  const int tid = threadIdx.x;
  const int l = blockIdx.x;
  const int oy = l / NWB, ox = l % NWB;

  for (int i = tid; i < 8*16*9; i += 64) {
    int oc2 = i / 144; int r = i - oc2*144; int ic = r / 9;
    int ky = (r % 9) / 3; int kx = r % 3;
    w2p[((oc2*16 + ic)*3 + ky)*4 + kx] = w2[i];
  }
  for (int i = tid; i < 200; i += 64) w3s[i] = w3[i];
  if (tid < 8) b2s[tid] = b2[tid];
  if (tid == 0) b3s_ = b3[0];
  __syncthreads();

  float ssum = 0.0f;
  for (int t = tid; t < 200; t += 64) {        // t = (oc2*5 + j)*5 + i5 == w3 index
    const int oc2 = t / 25; const int rem = t - oc2*25;
    const int j = rem / 5, i5 = rem - j*5;
    int gy[4], gx[4];
    #pragma unroll
    for (int d = 0; d < 4; ++d) {
      gy[d] = iclamp(10*oy - 1 + 2*j + d, 0, 639);   // edge_pad1 on x1p baked in
      gx[d] = iclamp(10*ox - 1 + 2*i5 + d, 0, 359);
    }
    float a00 = b2s[oc2], a01 = a00, a10 = a00, a11 = a00;
    for (int ic = 0; ic < 16; ++ic) {
      float p[4][4];
      #pragma unroll
      for (int d = 0; d < 4; ++d) {
        const float* rowp = &x1p[ic*X1N + gy[d]*360];
        #pragma unroll
        for (int e = 0; e < 4; ++e) p[d][e] = rowp[gx[e]];
      }
      #pragma unroll
      for (int ky = 0; ky < 3; ++ky) {
        float4 wq = *(const float4*)&w2p[((oc2*16 + ic)*3 + ky)*4];
        a00 += p[ky  ][0]*wq.x + p[ky  ][1]*wq.y + p[ky  ][2]*wq.z;
        a01 += p[ky  ][1]*wq.x + p[ky  ][2]*wq.y + p[ky  ][3]*wq.z;
        a10 += p[ky+1][0]*wq.x + p[ky+1][1]*wq.y + p[ky+1][2]*wq.z;
        a11 += p[ky+1][1]*wq.x + p[ky+1][2]*wq.y + p[ky+1][3]*wq.z;
      }
    }
    float x2 = fmaxf(fmaxf(a00, a01), fmaxf(a10, a11));
    ssum += x2 * w3s[t];
  }
  #pragma unroll
  for (int off = 32; off > 0; off >>= 1) ssum += __shfl_down(ssum, off);
  if (tid == 0)
    cv[l] = __fdividef(1.0f, 1.0f + __expf(-(ssum + b3s_)));
}

// ---------------------------------------------------------------------------
extern "C" void kernel_launch(void* const* d_in, const int* in_sizes, int n_in,
                              void* d_out, int out_size, void* d_ws, size_t ws_size,
                              hipStream_t stream) {
  const float* inp = (const float*)d_in[0];
  const float* w1  = (const float*)d_in[1];
  const float* b1  = (const float*)d_in[2];
  const float* w2  = (const float*)d_in[3];
  const float* b2  = (const float*)d_in[4];
  const float* w3  = (const float*)d_in[5];
  const float* b3  = (const float*)d_in[6];
  const float* wl  = (const float*)d_in[7];
  const float* bl  = (const float*)d_in[8];
  // d_in[9..14] = wc1..bc3: dead (gate sigmoid <= 1 -> mask always False)

  float* out = (float*)d_out;
  float* x1p = (float*)d_ws;   // [16][640][360] fp32 = 14.75 MB

  hipLaunchKernelGGL(k1_light_gateA, dim3(2*NBLK), dim3(256), 0, stream,
                     inp, w1, b1, wl, bl, out, x1p);
  hipLaunchKernelGGL(k2_gateBC, dim3(NBLK), dim3(64), 0, stream,
                     x1p, w2, b2, w3, b3, out + OUT_IMG);
}

// Round 6
// 308.801 us; speedup vs baseline: 1.5013x; 1.5013x over previous
//
#include <hip/hip_runtime.h>
#include <math.h>

// Problem constants
#define HH 1280
#define WW 720
#define NWB 36
#define NBLK 2304               // 64 x 36 block grid
#define OUT_IMG (3*5120*2880)   // 44236800

__device__ __forceinline__ int iclamp(int v, int lo, int hi) {
  return v < lo ? lo : (v > hi ? hi : v);
}
__device__ __forceinline__ float fast_tanh(float x) {
  float e = __expf(2.0f * x);
  return 1.0f - __fdividef(2.0f, e + 1.0f);
}

// ---------------------------------------------------------------------------
// K1: light expert. Per 20x20 block: zero-pad conv3x3 (3->48) + pixel_shuffle
// + clamp[0,0.6]+0.4 folded into [3][5120][2880]. One wg per block.
// mask = sigmoid(..) > 1.0 is always False -> complex expert is dead code.
// Outer conv loops are ROLLED (#pragma unroll 1) to keep the hot body ~2-3 KB
// (I$-resident); register-indexed inner loops stay unrolled.
// ---------------------------------------------------------------------------
__global__ __launch_bounds__(256) void k_light(
    const float* __restrict__ inp,
    const float* __restrict__ wl, const float* __restrict__ bl,
    float* __restrict__ out) {
  // row stride 28: h-stride 28 mod 32 = -4 -> b128 reads conflict-free
  __shared__ __align__(16) float in_s[3][22][28];
  __shared__ float w4[12*27*4];   // [ocg=(c*4+r1)][k][r2]
  __shared__ float bias[48];
  const int tid = threadIdx.x;
  const int l = blockIdx.x;
  const int bi = l / NWB, bj = l % NWB;

  for (int i = tid; i < 3*22*28; i += 256) ((float*)in_s)[i] = 0.0f;
  for (int i = tid; i < 48*27; i += 256) {
    int oc = i / 27, k = i - oc*27;
    w4[((oc >> 2)*27 + k)*4 + (oc & 3)] = wl[i];
  }
  if (tid < 48) bias[tid] = bl[tid];
  __syncthreads();
  for (int i = tid; i < 300; i += 256) {      // float4 global stage
    int x4 = i % 5, r = (i / 5) % 20, c = i / 100;
    float4 v = *(const float4*)&inp[(c*HH + bi*20 + r)*WW + bj*20 + 4*x4];
    float* dst = &in_s[c][r+1][1 + 4*x4];
    dst[0]=v.x; dst[1]=v.y; dst[2]=v.z; dst[3]=v.w;
  }
  __syncthreads();

  if (tid < 240) {
    // h-major: <=6 distinct row addrs per wave (12-lane broadcast each)
    const int h = tid / 12, ocg = tid % 12;
    const float4* wq = (const float4*)&w4[ocg*27*4];
    float acc0[20], acc1[20], acc2[20], acc3[20];
    {
      float b0 = bias[ocg*4+0], b1v = bias[ocg*4+1];
      float b2v = bias[ocg*4+2], b3v = bias[ocg*4+3];
      #pragma unroll
      for (int w = 0; w < 20; ++w) { acc0[w]=b0; acc1[w]=b1v; acc2[w]=b2v; acc3[w]=b3v; }
    }

    #pragma unroll 1
    for (int ic = 0; ic < 3; ++ic) {
      #pragma unroll 1
      for (int ky = 0; ky < 3; ++ky) {
        const float* row = &in_s[ic][h + ky][0];
        float r[24];
        #pragma unroll
        for (int j = 0; j < 6; ++j) {
          float4 v = ((const float4*)row)[j];   // ds_read_b128, conflict-free
          r[j*4+0]=v.x; r[j*4+1]=v.y; r[j*4+2]=v.z; r[j*4+3]=v.w;
        }
        float4 wa = wq[ic*9 + ky*3 + 0];
        float4 wb = wq[ic*9 + ky*3 + 1];
        float4 wc = wq[ic*9 + ky*3 + 2];
        #pragma unroll
        for (int w = 0; w < 20; ++w) {
          float x0 = r[w], x1 = r[w+1], x2 = r[w+2];
          acc0[w] += x0*wa.x + x1*wb.x + x2*wc.x;
          acc1[w] += x0*wa.y + x1*wb.y + x2*wc.y;
          acc2[w] += x0*wa.z + x1*wb.z + x2*wc.z;
          acc3[w] += x0*wa.w + x1*wb.w + x2*wc.w;
        }
      }
    }

    // pixel_shuffle: out[c][4h+r1][4w+r2]; r2 lanes -> float4 store
    const int c = ocg >> 2, r1 = ocg & 3;
    float4* obase = (float4*)&out[(c*5120 + bi*80 + 4*h + r1)*2880 + bj*80];
    #pragma unroll
    for (int w = 0; w < 20; ++w) {     // must stay unrolled (reg-array index)
      float4 v;
      v.x = fminf(fmaxf(acc0[w], 0.0f), 0.6f) + 0.4f;
      v.y = fminf(fmaxf(acc1[w], 0.0f), 0.6f) + 0.4f;
      v.z = fminf(fmaxf(acc2[w], 0.0f), 0.6f) + 0.4f;
      v.w = fminf(fmaxf(acc3[w], 0.0f), 0.6f) + 0.4f;
      obase[w] = v;
    }
  }
}

// ---------------------------------------------------------------------------
// K2: fused gate CNN, one wg per gate output, all stages LDS-resident.
//   A: conv1(3->16, edge-pad)+tanh+maxpool -> x1s[16][12][14]
//   B: conv2(16->8, edge-pad)+maxpool at the 5x5 window, product with w3
//   C: block reduction + sigmoid -> cv
// ---------------------------------------------------------------------------
__global__ __launch_bounds__(256) void k_gate(
    const float* __restrict__ inp,
    const float* __restrict__ w1, const float* __restrict__ b1,
    const float* __restrict__ w2, const float* __restrict__ b2,
    const float* __restrict__ w3, const float* __restrict__ b3,
    float* __restrict__ cv) {
  __shared__ float ins[3][26][28];    // clamped input patch (edge pad baked in)
  __shared__ float w1p[4*27*4];       // [ocg][k][r2]
  __shared__ float w2p[8*16*3*4];     // [oc2][ic][ky][kx0..2,pad]
  __shared__ float w3s[200];
  __shared__ float x1s[16][12][14];   // post-pool conv1 patch (stride 14, even)
  __shared__ float b1s[16];
  __shared__ float b2s[8];
  __shared__ float b3s_;
  __shared__ float red[256];

  const int tid = threadIdx.x;
  const int l = blockIdx.x;
  const int oy = l / NWB, ox = l % NWB;

  for (int i = tid; i < 16*27; i += 256) {
    int oc = i / 27, k = i - oc*27;
    w1p[((oc >> 2)*27 + k)*4 + (oc & 3)] = w1[i];
  }
  for (int i = tid; i < 8*16*9; i += 256) {
    int oc2 = i / 144; int r = i - oc2*144; int ic = r / 9;
    int ky = (r % 9) / 3; int kx = r % 3;
    w2p[((oc2*16 + ic)*3 + ky)*4 + kx] = w2[i];
  }
  for (int i = tid; i < 200; i += 256) w3s[i] = w3[i];
  if (tid < 16) b1s[tid] = b1[tid];
  if (tid < 8)  b2s[tid] = b2[tid];
  if (tid == 0) b3s_ = b3[0];

  // input patch rows/cols [20*o-3, 20*o+23), clamped (both edge_pads baked in)
  #pragma unroll 1
  for (int i = tid; i < 3*26*28; i += 256) {
    int b = i % 28; int a = (i / 28) % 26; int ic = i / (26*28);
    int gy = iclamp(20*oy - 3 + a, 0, HH-1);
    int gx = iclamp(20*ox - 3 + b, 0, WW-1);
    ins[ic][a][b] = inp[(ic*HH + gy)*WW + gx];
  }
  __syncthreads();

  // ---- stage A: conv1 + tanh + maxpool, 4-oc blocked. 576 tasks.
  #pragma unroll 1
  for (int t = tid; t < 576; t += 256) {
    const int ocg = t / 144; const int pos = t - ocg*144;
    const int ly = pos / 12, lx = pos - ly*12;
    const int y1 = iclamp(10*oy - 1 + ly, 0, 639);
    const int x1 = iclamp(10*ox - 1 + lx, 0, 359);
    const int ry = 2*y1 + 2 - 20*oy;   // even, in [0,22]
    const int rx = 2*x1 + 2 - 20*ox;   // even
    const float4* wv = (const float4*)&w1p[ocg*27*4];
    float acc[4][4];   // [window][r2]
    #pragma unroll
    for (int win = 0; win < 4; ++win)
      #pragma unroll
      for (int r = 0; r < 4; ++r) acc[win][r] = b1s[ocg*4 + r];
    #pragma unroll 1
    for (int ic = 0; ic < 3; ++ic) {
      float p[4][4];
      #pragma unroll
      for (int d = 0; d < 4; ++d) {
        float2 u = *(const float2*)&ins[ic][ry+d][rx];     // 8B-aligned
        float2 v = *(const float2*)&ins[ic][ry+d][rx+2];
        p[d][0]=u.x; p[d][1]=u.y; p[d][2]=v.x; p[d][3]=v.y;
      }
      #pragma unroll
      for (int ky = 0; ky < 3; ++ky)
        #pragma unroll
        for (int kx = 0; kx < 3; ++kx) {
          float4 wq = wv[ic*9 + ky*3 + kx];
          #pragma unroll
          for (int sy = 0; sy < 2; ++sy)
            #pragma unroll
            for (int sx = 0; sx < 2; ++sx) {
              float pv = p[sy+ky][sx+kx];
              acc[sy*2+sx][0] += pv*wq.x;
              acc[sy*2+sx][1] += pv*wq.y;
              acc[sy*2+sx][2] += pv*wq.z;
              acc[sy*2+sx][3] += pv*wq.w;
            }
        }
    }
    #pragma unroll
    for (int r = 0; r < 4; ++r) {
      float m = fmaxf(fmaxf(acc[0][r], acc[1][r]), fmaxf(acc[2][r], acc[3][r]));
      x1s[ocg*4 + r][ly][lx] = fast_tanh(m);   // maxpool(tanh)==tanh(maxpool)
    }
  }
  __syncthreads();

  // ---- stage B: conv2 + maxpool at the 5x5 window; product with w3
  float prod = 0.0f;
  if (tid < 200) {
    const int oc2 = tid / 25; const int rem = tid - oc2*25;
    const int j = rem / 5, i5 = rem - j*5;
    float a00 = b2s[oc2], a01 = a00, a10 = a00, a11 = a00;
    #pragma unroll 1
    for (int ic = 0; ic < 16; ++ic) {
      float p[4][4];
      #pragma unroll
      for (int d = 0; d < 4; ++d) {
        float2 u = *(const float2*)&x1s[ic][2*j + d][2*i5];
        float2 v = *(const float2*)&x1s[ic][2*j + d][2*i5 + 2];
        p[d][0]=u.x; p[d][1]=u.y; p[d][2]=v.x; p[d][3]=v.y;
      }
      #pragma unroll
      for (int ky = 0; ky < 3; ++ky) {
        float4 wq = *(const float4*)&w2p[((oc2*16 + ic)*3 + ky)*4];
        a00 += p[ky  ][0]*wq.x + p[ky  ][1]*wq.y + p[ky  ][2]*wq.z;
        a01 += p[ky  ][1]*wq.x + p[ky  ][2]*wq.y + p[ky  ][3]*wq.z;
        a10 += p[ky+1][0]*wq.x + p[ky+1][1]*wq.y + p[ky+1][2]*wq.z;
        a11 += p[ky+1][1]*wq.x + p[ky+1][2]*wq.y + p[ky+1][3]*wq.z;
      }
    }
    float x2 = fmaxf(fmaxf(a00, a01), fmaxf(a10, a11));
    prod = x2 * w3s[tid];
  }
  red[tid] = prod;
  __syncthreads();

  // ---- stage C
  if (tid < 64) {
    float s = red[tid] + red[tid+64] + red[tid+128] + red[tid+192];
    #pragma unroll
    for (int off = 32; off > 0; off >>= 1) s += __shfl_down(s, off);
    if (tid == 0)
      cv[l] = __fdividef(1.0f, 1.0f + __expf(-(s + b3s_)));
  }
}

// ---------------------------------------------------------------------------
extern "C" void kernel_launch(void* const* d_in, const int* in_sizes, int n_in,
                              void* d_out, int out_size, void* d_ws, size_t ws_size,
                              hipStream_t stream) {
  const float* inp = (const float*)d_in[0];
  const float* w1  = (const float*)d_in[1];
  const float* b1  = (const float*)d_in[2];
  const float* w2  = (const float*)d_in[3];
  const float* b2  = (const float*)d_in[4];
  const float* w3  = (const float*)d_in[5];
  const float* b3  = (const float*)d_in[6];
  const float* wl  = (const float*)d_in[7];
  const float* bl  = (const float*)d_in[8];
  // d_in[9..14] = wc1..bc3: dead (gate sigmoid <= 1 -> mask always False)

  float* out = (float*)d_out;

  hipLaunchKernelGGL(k_light, dim3(NBLK), dim3(256), 0, stream, inp, wl, bl, out);
  hipLaunchKernelGGL(k_gate, dim3(NBLK), dim3(256), 0, stream,
                     inp, w1, b1, w2, b2, w3, b3, out + OUT_IMG);
}